// Round 4
// baseline (107.908 us; speedup 1.0000x reference)
//
#include <hip/hip_runtime.h>
#include <stdint.h>

// GAT layer: N=4096 nodes, IN=256, H=4 heads, F=64 out/head.
constexpr int NODES = 4096;
constexpr int KIN   = 256;
constexpr int NHEAD = 4;
constexpr int NF    = 64;
constexpr int HFQ   = 256;   // NHEAD*NF
#define SLOPE 0.2f
#define L2E 1.44269504088896340736f

typedef __attribute__((ext_vector_type(8))) short short8;
typedef __attribute__((ext_vector_type(4))) float floatx4;
typedef __attribute__((ext_vector_type(16))) float f32x16;

static __device__ __forceinline__ unsigned short f2bf(float f) {
  return __builtin_bit_cast(unsigned short, (__bf16)f);
}

// ---- kernel 1: fp32 -> bf16 conversion of h and W --------------------------
__global__ __launch_bounds__(256) void prep_kernel(
    const float* __restrict__ hin, const float* __restrict__ Win,
    unsigned short* __restrict__ hB, unsigned short* __restrict__ WB) {
  int idx = blockIdx.x * 256 + threadIdx.x;           // float4 index
  const int NH4 = (NODES * KIN) / 4;                  // 262144
  const int NW4 = (HFQ * KIN) / 4;                    // 16384
  if (idx < NH4) {
    float4 v = reinterpret_cast<const float4*>(hin)[idx];
    ushort4 o = { f2bf(v.x), f2bf(v.y), f2bf(v.z), f2bf(v.w) };
    reinterpret_cast<ushort4*>(hB)[idx] = o;
  } else if (idx < NH4 + NW4) {
    int j = idx - NH4;
    float4 v = reinterpret_cast<const float4*>(Win)[j];
    ushort4 o = { f2bf(v.x), f2bf(v.y), f2bf(v.z), f2bf(v.w) };
    reinterpret_cast<ushort4*>(WB)[j] = o;
  }
}

// ---- kernel 2: projection g = h @ W^T + b  (MFMA 16x16x32 bf16) ------------
// writes g32 [NODES][HFQ] fp32 and gT2 tiled bf16: gT2[jt][c][jj],
// element (node j, feature c) at  (j>>5)*8192 + c*32 + (j&31).
__global__ __launch_bounds__(256) void proj_kernel(
    const unsigned short* __restrict__ hB, const unsigned short* __restrict__ WB,
    const float* __restrict__ bias,
    float* __restrict__ g32, unsigned short* __restrict__ gT2) {
  int wave = threadIdx.x >> 6, lane = threadIdx.x & 63;
  int tile = blockIdx.x * 4 + wave;       // 4096 tiles = 256 mtiles x 16 ntiles
  int mt = tile >> 4, nt = tile & 15;
  int m0 = mt * 16, n0 = nt * 16;
  int r = lane & 15, kg = lane >> 4;
  floatx4 acc = {0.f, 0.f, 0.f, 0.f};
  const short8* Ap = reinterpret_cast<const short8*>(hB + (m0 + r) * KIN + kg * 8);
  const short8* Bp = reinterpret_cast<const short8*>(WB + (n0 + r) * KIN + kg * 8);
#pragma unroll
  for (int kb = 0; kb < 8; ++kb) {
    short8 a = Ap[kb * 4];   // advance 32 shorts per K-step
    short8 b = Bp[kb * 4];
    acc = __builtin_amdgcn_mfma_f32_16x16x32_bf16(a, b, acc, 0, 0, 0);
  }
  int col = n0 + r;
  float bv = bias[col];
#pragma unroll
  for (int q = 0; q < 4; ++q) {
    int row = m0 + kg * 4 + q;            // C/D layout: row=(lane>>4)*4+reg, col=lane&15
    float v = acc[q] + bv;
    g32[row * HFQ + col] = v;
    gT2[(row >> 5) * (HFQ * 32) + col * 32 + (row & 31)] = f2bf(v);
  }
}

// ---- kernel 3: src/dst per (node, head) -> factorized exp terms ------------
// srcP[n][h] = (es1, es2, thr) = (exp(s), exp(0.2s), exp(-s)), s incl. bias
// ed1P[h][n] = exp(d), ed2P[h][n] = exp(0.2d)
__global__ __launch_bounds__(256) void srcdst_kernel(
    const float* __restrict__ g32, const float* __restrict__ attn_w,
    const float* __restrict__ attn_b,
    float4* __restrict__ srcP, float* __restrict__ ed1P, float* __restrict__ ed2P) {
  int wave = threadIdx.x >> 6, lane = threadIdx.x & 63;
  int n = blockIdx.x * 4 + wave;
  float aws = attn_w[lane], awd = attn_w[64 + lane];
  float ab = attn_b[0];
#pragma unroll
  for (int hh = 0; hh < NHEAD; ++hh) {
    float v = g32[n * HFQ + hh * NF + lane];
    float s = v * aws, d = v * awd;
#pragma unroll
    for (int m = 32; m >= 1; m >>= 1) {
      s += __shfl_xor(s, m, 64);
      d += __shfl_xor(d, m, 64);
    }
    if (lane == 0) {
      s += ab;
      float4 sp;
      sp.x = exp2f(s * L2E);
      sp.y = exp2f(0.2f * s * L2E);
      sp.z = exp2f(-s * L2E);
      sp.w = 0.f;
      srcP[n * NHEAD + hh] = sp;
      ed1P[hh * NODES + n] = exp2f(d * L2E);
      ed2P[hh * NODES + n] = exp2f(0.2f * d * L2E);
    }
  }
}

// ---- kernel 4: fused attention, 32x32x16 MFMA, LDS-free, barrier-free ------
// grid (128 row-tiles of 32, NP j-partitions), block 256 = 4 waves (1 head ea).
// D[c][i] = sum_j g[c,j] * w[j,i]:  A = g-tile (from gT2), B = w in-register.
// B layout: n = lane&31 = attn row i, k = 8*(lane>>5)+r = j within chunk.
// w = (ed1 >= thr) ? es1*ed1 : es2*ed2, masked by adj. Denominator via a
// ones-A MFMA (row sums on the matrix pipe).
// adj (the only HBM-streaming operand) is double-buffered in registers with
// a one-step prefetch distance to hide its ~300-900 cy latency.
__global__ __launch_bounds__(256, 4) void attn_kernel(
    const int* __restrict__ adj, const unsigned short* __restrict__ gT2,
    const float4* __restrict__ srcP,
    const float* __restrict__ ed1P, const float* __restrict__ ed2P,
    float* __restrict__ pnum, float* __restrict__ pden, int JP) {
  int tid = threadIdx.x;
  int hh = tid >> 6, lane = tid & 63;
  int il = lane & 31, hi = lane >> 5;
  int part = blockIdx.y, jstart = part * JP;
  int i = blockIdx.x * 32 + il;           // attention row this lane owns

  float4 sp = srcP[i * NHEAD + hh];
  float es1 = sp.x, es2 = sp.y, thr = sp.z;

  f32x16 acc0 = {0.f,0.f,0.f,0.f,0.f,0.f,0.f,0.f,0.f,0.f,0.f,0.f,0.f,0.f,0.f,0.f};
  f32x16 acc1 = acc0, accd = acc0;

  short8 ones;
#pragma unroll
  for (int r = 0; r < 8; ++r) ones[r] = (short)0x3F80;  // bf16 1.0

  const float* e1base = ed1P + hh * NODES;
  const float* e2base = ed2P + hh * NODES;
  const int* adjrow = adj + (size_t)i * NODES + hi * 8;
  const unsigned short* tA0 = gT2 + (hh * 64 + il) * 32 + hi * 8;
  const unsigned short* tA1 = tA0 + 32 * 32;

  int nsteps = JP / 32;   // NP in {2,4,8} -> nsteps in {64,32,16}: always even

  // adj register double-buffer: 4 int4 per step (2 chunks x 32B)
#define LOAD_ADJ(RA, RB, RC, RD, STP) {                         \
    const int* p_ = adjrow + jstart + (STP) * 32;               \
    RA = *reinterpret_cast<const int4*>(p_);                    \
    RB = *reinterpret_cast<const int4*>(p_ + 4);                \
    RC = *reinterpret_cast<const int4*>(p_ + 16);               \
    RD = *reinterpret_cast<const int4*>(p_ + 20);               \
  }

#define COMPUTE_STEP(RA, RB, RC, RD, STP) {                                     \
    int j0_ = jstart + (STP) * 32;                                              \
    size_t toff_ = (size_t)(j0_ >> 5) * (HFQ * 32);                             \
    _Pragma("unroll")                                                           \
    for (int ch = 0; ch < 2; ++ch) {                                            \
      int jc_ = j0_ + ch * 16 + hi * 8;                                         \
      float4 e1a = *reinterpret_cast<const float4*>(e1base + jc_);              \
      float4 e1b = *reinterpret_cast<const float4*>(e1base + jc_ + 4);          \
      float4 e2a = *reinterpret_cast<const float4*>(e2base + jc_);              \
      float4 e2b = *reinterpret_cast<const float4*>(e2base + jc_ + 4);          \
      int4 aa_ = ch ? RC : RA;                                                  \
      int4 ab_ = ch ? RD : RB;                                                  \
      float e1v[8] = {e1a.x, e1a.y, e1a.z, e1a.w, e1b.x, e1b.y, e1b.z, e1b.w};  \
      float e2v[8] = {e2a.x, e2a.y, e2a.z, e2a.w, e2b.x, e2b.y, e2b.z, e2b.w};  \
      int   av_[8] = {aa_.x, aa_.y, aa_.z, aa_.w, ab_.x, ab_.y, ab_.z, ab_.w};  \
      short8 bfr;                                                               \
      _Pragma("unroll")                                                         \
      for (int r = 0; r < 8; ++r) {                                             \
        bool sel = e1v[r] >= thr;                                               \
        float w = (sel ? es1 : es2) * (sel ? e1v[r] : e2v[r]);                  \
        w = (av_[r] != 0) ? w : 0.f;                                            \
        bfr[r] = (short)f2bf(w);                                                \
      }                                                                         \
      const short8 a0 = *reinterpret_cast<const short8*>(tA0 + toff_ + ch * 16);\
      const short8 a1 = *reinterpret_cast<const short8*>(tA1 + toff_ + ch * 16);\
      acc0 = __builtin_amdgcn_mfma_f32_32x32x16_bf16(a0, bfr, acc0, 0, 0, 0);   \
      acc1 = __builtin_amdgcn_mfma_f32_32x32x16_bf16(a1, bfr, acc1, 0, 0, 0);   \
      accd = __builtin_amdgcn_mfma_f32_32x32x16_bf16(ones, bfr, accd, 0, 0, 0); \
    }                                                                           \
  }

  int4 bA0, bA1, bA2, bA3;   // buffer A
  int4 bB0, bB1, bB2, bB3;   // buffer B
  LOAD_ADJ(bA0, bA1, bA2, bA3, 0);
  for (int stp = 0; stp + 2 <= nsteps; stp += 2) {
    LOAD_ADJ(bB0, bB1, bB2, bB3, stp + 1);
    COMPUTE_STEP(bA0, bA1, bA2, bA3, stp);
    if (stp + 2 < nsteps) LOAD_ADJ(bA0, bA1, bA2, bA3, stp + 2);
    COMPUTE_STEP(bB0, bB1, bB2, bB3, stp + 1);
  }
#undef LOAD_ADJ
#undef COMPUTE_STEP

  // denominator: all rows of accd identical; col = il
  if (hi == 0)
    pden[(size_t)part * (NODES * NHEAD) + i * NHEAD + hh] = accd[0];

  // numerator: C layout col=lane&31 (=i), row c = (reg&3)+8*(reg>>2)+4*hi
  float* pbase = pnum + (size_t)part * (NODES * HFQ) + (size_t)i * HFQ + hh * NF;
#pragma unroll
  for (int reg = 0; reg < 16; ++reg) {
    int crow = (reg & 3) + 8 * (reg >> 2) + 4 * hi;
    pbase[crow] = acc0[reg];
    pbase[32 + crow] = acc1[reg];
  }
}

// ---- kernel 5: combine partials, normalize, mean over heads ----------------
__global__ __launch_bounds__(256) void combine_kernel(
    const float* __restrict__ pnum, const float* __restrict__ pden,
    float* __restrict__ out, int NP) {
  int idx = blockIdx.x * 256 + threadIdx.x;
  int i = idx >> 6, f = idx & 63;
  float o = 0.f;
#pragma unroll
  for (int hh = 0; hh < NHEAD; ++hh) {
    float num = 0.f, den = 0.f;
    for (int p = 0; p < NP; ++p) {
      num += pnum[p * (NODES * HFQ) + i * HFQ + hh * NF + f];
      den += pden[p * (NODES * NHEAD) + i * NHEAD + hh];
    }
    o += num / den;
  }
  out[idx] = 0.25f * o;
}

extern "C" void kernel_launch(void* const* d_in, const int* in_sizes, int n_in,
                              void* d_out, int out_size, void* d_ws, size_t ws_size,
                              hipStream_t stream) {
  const float* hin = (const float*)d_in[0];
  const int* adj   = (const int*)d_in[1];
  const float* W   = (const float*)d_in[2];
  const float* b   = (const float*)d_in[3];
  const float* aw  = (const float*)d_in[4];
  const float* ab  = (const float*)d_in[5];
  float* out = (float*)d_out;
  char* ws = (char*)d_ws;

  unsigned short* hB  = (unsigned short*)(ws + 0x000000);  // 2 MB
  unsigned short* WB  = (unsigned short*)(ws + 0x200000);  // 128 KB
  float* g32          = (float*)(ws + 0x400000);           // 4 MB
  unsigned short* gT2 = (unsigned short*)(ws + 0x800000);  // 2 MB (tiled)
  float4* srcP        = (float4*)(ws + 0xA00000);          // 256 KB
  float* ed1P         = (float*)(ws + 0xA40000);           // 64 KB
  float* ed2P         = (float*)(ws + 0xA50000);           // 64 KB
  float* pden         = (float*)(ws + 0xA60000);           // up to 512 KB
  float* pnum         = (float*)(ws + 0xB00000);           // NP * 4 MB
  const size_t base = 0xB00000;

  int NP = 2;
  if (ws_size >= base + 8ull * NODES * HFQ * 4) NP = 8;
  else if (ws_size >= base + 4ull * NODES * HFQ * 4) NP = 4;
  int JP = NODES / NP;

  prep_kernel<<<1088, 256, 0, stream>>>(hin, W, hB, WB);
  proj_kernel<<<1024, 256, 0, stream>>>(hB, WB, b, g32, gT2);
  srcdst_kernel<<<1024, 256, 0, stream>>>(g32, aw, ab, srcP, ed1P, ed2P);
  attn_kernel<<<dim3(128, NP), 256, 0, stream>>>(adj, gT2, srcP, ed1P, ed2P, pnum, pden, JP);
  combine_kernel<<<1024, 256, 0, stream>>>(pnum, pden, out, NP);
}

// Round 5
// 82.183 us; speedup vs baseline: 1.3130x; 1.3130x over previous
//
#include <hip/hip_runtime.h>
#include <stdint.h>

// GAT layer: N=4096 nodes, IN=256, H=4 heads, F=64 out/head.
constexpr int NODES = 4096;
constexpr int KIN   = 256;
constexpr int NHEAD = 4;
constexpr int NF    = 64;
constexpr int HFQ   = 256;   // NHEAD*NF
#define SLOPE 0.2f
#define L2E 1.44269504088896340736f

typedef __attribute__((ext_vector_type(8))) short short8;
typedef __attribute__((ext_vector_type(4))) float floatx4;
typedef __attribute__((ext_vector_type(16))) float f32x16;

static __device__ __forceinline__ unsigned short f2bf(float f) {
  return __builtin_bit_cast(unsigned short, (__bf16)f);
}

// ---- kernel 1: adjacency -> transposed bitmask  +  fp32->bf16 prep ---------
// bm[jw][i] bit b = (adj[i][jw*32+b] != 0).  bm is 2 MB -> L2-resident.
// Blocks < 2048: pack. Blocks >= 2048: bf16 conversion of h and W.
__global__ __launch_bounds__(256) void pack_prep_kernel(
    const int* __restrict__ adj, unsigned* __restrict__ bm,
    const float* __restrict__ hin, const float* __restrict__ Win,
    unsigned short* __restrict__ hB, unsigned short* __restrict__ WB) {
  int tid = threadIdx.x;
  if (blockIdx.x < 2048) {
    int wv = blockIdx.x * 4 + (tid >> 6);   // 8192 waves
    int lane = tid & 63;
    int jw = wv & 127;                      // j-word (32 j's)
    int it = wv >> 7;                       // i-tile of 64
    int i = it * 64 + lane;
    // lane reads its row's 32 adj ints (128 B contiguous); writes coalesced.
    const int4* p = reinterpret_cast<const int4*>(adj + (size_t)i * NODES + jw * 32);
    unsigned m = 0;
#pragma unroll
    for (int q = 0; q < 8; ++q) {
      int4 a = p[q];
      m |= (a.x != 0 ? 1u : 0u) << (q * 4);
      m |= (a.y != 0 ? 1u : 0u) << (q * 4 + 1);
      m |= (a.z != 0 ? 1u : 0u) << (q * 4 + 2);
      m |= (a.w != 0 ? 1u : 0u) << (q * 4 + 3);
    }
    bm[(size_t)jw * NODES + i] = m;
  } else {
    int idx = (blockIdx.x - 2048) * 256 + tid;  // float4 index
    const int NH4 = (NODES * KIN) / 4;          // 262144
    const int NW4 = (HFQ * KIN) / 4;            // 16384
    if (idx < NH4) {
      float4 v = reinterpret_cast<const float4*>(hin)[idx];
      ushort4 o = { f2bf(v.x), f2bf(v.y), f2bf(v.z), f2bf(v.w) };
      reinterpret_cast<ushort4*>(hB)[idx] = o;
    } else if (idx < NH4 + NW4) {
      int j = idx - NH4;
      float4 v = reinterpret_cast<const float4*>(Win)[j];
      ushort4 o = { f2bf(v.x), f2bf(v.y), f2bf(v.z), f2bf(v.w) };
      reinterpret_cast<ushort4*>(WB)[j] = o;
    }
  }
}

// ---- kernel 2: projection g = h @ W^T + b  (MFMA 16x16x32 bf16) ------------
// writes g32 [NODES][HFQ] fp32 and gT3: MFMA-A-fragment-ordered bf16 so attn's
// wave loads are contiguous 1 KB. Element (node j, col c):
//   jt=j>>5, ch=(j>>4)&1, hi=(j>>3)&1, r=j&7, head=c>>6, half=(c>>5)&1, il=c&31
//   short index = jt*8192 + head*2048 + half*1024 + ch*512 + hi*256 + il*8 + r
__global__ __launch_bounds__(256) void proj_kernel(
    const unsigned short* __restrict__ hB, const unsigned short* __restrict__ WB,
    const float* __restrict__ bias,
    float* __restrict__ g32, unsigned short* __restrict__ gT3) {
  int wave = threadIdx.x >> 6, lane = threadIdx.x & 63;
  int tile = blockIdx.x * 4 + wave;       // 4096 tiles = 256 mtiles x 16 ntiles
  int mt = tile >> 4, nt = tile & 15;
  int m0 = mt * 16, n0 = nt * 16;
  int r = lane & 15, kg = lane >> 4;
  floatx4 acc = {0.f, 0.f, 0.f, 0.f};
  const short8* Ap = reinterpret_cast<const short8*>(hB + (m0 + r) * KIN + kg * 8);
  const short8* Bp = reinterpret_cast<const short8*>(WB + (n0 + r) * KIN + kg * 8);
#pragma unroll
  for (int kb = 0; kb < 8; ++kb) {
    short8 a = Ap[kb * 4];   // advance 32 shorts per K-step
    short8 b = Bp[kb * 4];
    acc = __builtin_amdgcn_mfma_f32_16x16x32_bf16(a, b, acc, 0, 0, 0);
  }
  int col = n0 + r;
  float bv = bias[col];
  int head = col >> 6, half = (col >> 5) & 1, il = col & 31;
#pragma unroll
  for (int q = 0; q < 4; ++q) {
    int row = m0 + kg * 4 + q;            // C/D layout: row=(lane>>4)*4+reg, col=lane&15
    float v = acc[q] + bv;
    g32[row * HFQ + col] = v;
    int si = (row >> 5) * 8192 + head * 2048 + half * 1024 +
             ((row >> 4) & 1) * 512 + ((row >> 3) & 1) * 256 + il * 8 + (row & 7);
    gT3[si] = f2bf(v);
  }
}

// ---- kernel 3: src/dst per (node, head) -> factorized exp terms ------------
// srcP[n][h] = (exp(s), exp(0.2s), exp(-s), 0), s incl. bias
// eP[h][n]   = (bf16(exp(0.2d)) << 16) | bf16(exp(d))   -- 64 KB, L1-resident
__global__ __launch_bounds__(256) void srcdst_kernel(
    const float* __restrict__ g32, const float* __restrict__ attn_w,
    const float* __restrict__ attn_b,
    float4* __restrict__ srcP, unsigned* __restrict__ eP) {
  int wave = threadIdx.x >> 6, lane = threadIdx.x & 63;
  int n = blockIdx.x * 4 + wave;
  float aws = attn_w[lane], awd = attn_w[64 + lane];
  float ab = attn_b[0];
#pragma unroll
  for (int hh = 0; hh < NHEAD; ++hh) {
    float v = g32[n * HFQ + hh * NF + lane];
    float s = v * aws, d = v * awd;
#pragma unroll
    for (int m = 32; m >= 1; m >>= 1) {
      s += __shfl_xor(s, m, 64);
      d += __shfl_xor(d, m, 64);
    }
    if (lane == 0) {
      s += ab;
      float4 sp;
      sp.x = exp2f(s * L2E);
      sp.y = exp2f(0.2f * s * L2E);
      sp.z = exp2f(-s * L2E);
      sp.w = 0.f;
      srcP[n * NHEAD + hh] = sp;
      float e1 = exp2f(d * L2E), e2 = exp2f(0.2f * d * L2E);
      eP[hh * NODES + n] = ((unsigned)f2bf(e2) << 16) | (unsigned)f2bf(e1);
    }
  }
}

// ---- kernel 4: fused attention, 32x32x16 MFMA, all loads coalesced ---------
// grid (NP, 128): blockIdx.x = j-partition (linear%8 -> one partition per XCD),
// blockIdx.y = i-tile of 32 rows. block 256 = 4 waves (1 head each).
// D[c][i] = sum_j g[c,j]*w[j,i]: A = g (gT3, contiguous), B = w in-register.
// B layout: lane&31 = i, k = 8*(lane>>5)+r = j. w from packed bf16 exp table +
// bitmask; denominator via ones-A MFMA.
__global__ __launch_bounds__(256, 4) void attn_kernel(
    const unsigned* __restrict__ bm, const unsigned short* __restrict__ gT3,
    const float4* __restrict__ srcP, const unsigned* __restrict__ eP,
    float* __restrict__ pnum, float* __restrict__ pden, int JP) {
  int tid = threadIdx.x;
  int hh = tid >> 6, lane = tid & 63;
  int il = lane & 31, hi = lane >> 5;
  int part = blockIdx.x, itile = blockIdx.y;
  int jstart = part * JP;
  int i = itile * 32 + il;                // attention row this lane owns

  float4 sp = srcP[i * NHEAD + hh];
  float es1 = sp.x, es2 = sp.y, thr = sp.z;

  f32x16 acc0 = {0.f,0.f,0.f,0.f,0.f,0.f,0.f,0.f,0.f,0.f,0.f,0.f,0.f,0.f,0.f,0.f};
  f32x16 acc1 = acc0, accd = acc0;

  short8 ones;
#pragma unroll
  for (int r = 0; r < 8; ++r) ones[r] = (short)0x3F80;  // bf16 1.0

  const unsigned* epb = eP + hh * NODES;
  const unsigned short* Ab = gT3 + hh * 2048;

  int nsteps = JP / 32;
  for (int stp = 0; stp < nsteps; ++stp) {
    int j0 = jstart + stp * 32;
    unsigned mwd = bm[(size_t)(j0 >> 5) * NODES + i];       // coalesced dword
    const unsigned short* At = Ab + (size_t)(j0 >> 5) * 8192;
#pragma unroll
    for (int ch = 0; ch < 2; ++ch) {
      int jc = j0 + ch * 16 + hi * 8;
      uint4 ea = *reinterpret_cast<const uint4*>(epb + jc);      // broadcast
      uint4 eb = *reinterpret_cast<const uint4*>(epb + jc + 4);
      unsigned mb = (mwd >> (ch * 16 + hi * 8)) & 0xFFu;
      unsigned ev[8] = {ea.x, ea.y, ea.z, ea.w, eb.x, eb.y, eb.z, eb.w};
      short8 bfr;
#pragma unroll
      for (int r = 0; r < 8; ++r) {
        float e1f = __builtin_bit_cast(float, ev[r] << 16);
        float e2f = __builtin_bit_cast(float, ev[r] & 0xFFFF0000u);
        bool sel = e1f >= thr;
        float w = (sel ? es1 : es2) * (sel ? e1f : e2f);
        w = (mb & (1u << r)) ? w : 0.f;
        bfr[r] = (short)f2bf(w);
      }
      const short8 a0 = *reinterpret_cast<const short8*>(At + ch * 512 + hi * 256 + il * 8);
      const short8 a1 = *reinterpret_cast<const short8*>(At + 1024 + ch * 512 + hi * 256 + il * 8);
      acc0 = __builtin_amdgcn_mfma_f32_32x32x16_bf16(a0, bfr, acc0, 0, 0, 0);
      acc1 = __builtin_amdgcn_mfma_f32_32x32x16_bf16(a1, bfr, acc1, 0, 0, 0);
      accd = __builtin_amdgcn_mfma_f32_32x32x16_bf16(ones, bfr, accd, 0, 0, 0);
    }
  }

  // denominator: all rows of accd identical; col = il
  if (hi == 0)
    pden[(size_t)part * (NODES * NHEAD) + i * NHEAD + hh] = accd[0];

  // numerator: C layout col=lane&31 (=i), row c = (reg&3)+8*(reg>>2)+4*hi
  float* pbase = pnum + (size_t)part * (NODES * HFQ) + (size_t)i * HFQ + hh * NF;
#pragma unroll
  for (int reg = 0; reg < 16; ++reg) {
    int crow = (reg & 3) + 8 * (reg >> 2) + 4 * hi;
    pbase[crow] = acc0[reg];
    pbase[32 + crow] = acc1[reg];
  }
}

// ---- kernel 5: combine partials, normalize, mean over heads ----------------
__global__ __launch_bounds__(256) void combine_kernel(
    const float* __restrict__ pnum, const float* __restrict__ pden,
    float* __restrict__ out, int NP) {
  int idx = blockIdx.x * 256 + threadIdx.x;
  int i = idx >> 6, f = idx & 63;
  float o = 0.f;
#pragma unroll
  for (int hh = 0; hh < NHEAD; ++hh) {
    float num = 0.f, den = 0.f;
    for (int p = 0; p < NP; ++p) {
      num += pnum[p * (NODES * HFQ) + i * HFQ + hh * NF + f];
      den += pden[p * (NODES * NHEAD) + i * NHEAD + hh];
    }
    o += num / den;
  }
  out[idx] = 0.25f * o;
}

extern "C" void kernel_launch(void* const* d_in, const int* in_sizes, int n_in,
                              void* d_out, int out_size, void* d_ws, size_t ws_size,
                              hipStream_t stream) {
  const float* hin = (const float*)d_in[0];
  const int* adj   = (const int*)d_in[1];
  const float* W   = (const float*)d_in[2];
  const float* b   = (const float*)d_in[3];
  const float* aw  = (const float*)d_in[4];
  const float* ab  = (const float*)d_in[5];
  float* out = (float*)d_out;
  char* ws = (char*)d_ws;

  unsigned short* hB  = (unsigned short*)(ws + 0x000000);  // 2 MB
  unsigned short* WB  = (unsigned short*)(ws + 0x200000);  // 128 KB
  float* g32          = (float*)(ws + 0x400000);           // 4 MB
  unsigned short* gT3 = (unsigned short*)(ws + 0x800000);  // 2 MB (frag-ordered)
  float4* srcP        = (float4*)(ws + 0xA00000);          // 256 KB
  unsigned* eP        = (unsigned*)(ws + 0xA40000);        // 64 KB
  unsigned* bm        = (unsigned*)(ws + 0xA60000);        // 2 MB bitmask
  float* pden         = (float*)(ws + 0xC60000);           // up to 512 KB
  float* pnum         = (float*)(ws + 0xD00000);           // NP * 4 MB
  const size_t base = 0xD00000;

  int NP = 2;
  if (ws_size >= base + 8ull * NODES * HFQ * 4) NP = 8;
  else if (ws_size >= base + 4ull * NODES * HFQ * 4) NP = 4;
  int JP = NODES / NP;

  pack_prep_kernel<<<2048 + 1088, 256, 0, stream>>>(adj, bm, hin, W, hB, WB);
  proj_kernel<<<1024, 256, 0, stream>>>(hB, WB, b, g32, gT3);
  srcdst_kernel<<<1024, 256, 0, stream>>>(g32, aw, ab, srcP, eP);
  attn_kernel<<<dim3(NP, 128), 256, 0, stream>>>(bm, gT3, srcP, eP, pnum, pden, JP);
  combine_kernel<<<1024, 256, 0, stream>>>(pnum, pden, out, NP);
}

// Round 6
// 80.930 us; speedup vs baseline: 1.3333x; 1.0155x over previous
//
#include <hip/hip_runtime.h>
#include <stdint.h>

// GAT layer: N=4096 nodes, IN=256, H=4 heads, F=64 out/head.
constexpr int NODES = 4096;
constexpr int KIN   = 256;
constexpr int NHEAD = 4;
constexpr int NF    = 64;
constexpr int HFQ   = 256;   // NHEAD*NF
#define SLOPE 0.2f
#define L2E 1.44269504088896340736f

typedef __attribute__((ext_vector_type(8))) short short8;
typedef __attribute__((ext_vector_type(4))) float floatx4;

static __device__ __forceinline__ unsigned short f2bf(float f) {
  return __builtin_bit_cast(unsigned short, (__bf16)f);
}

// ---- kernel 1: adjacency -> transposed bitmask  +  fp32->bf16 prep ---------
// bm[jw][i] bit b = (adj[i][jw*32+b] != 0).  bm is 2 MB -> L2-resident.
// Blocks < 2048: pack. Blocks >= 2048: bf16 conversion of h and W.
__global__ __launch_bounds__(256) void pack_prep_kernel(
    const int* __restrict__ adj, unsigned* __restrict__ bm,
    const float* __restrict__ hin, const float* __restrict__ Win,
    unsigned short* __restrict__ hB, unsigned short* __restrict__ WB) {
  int tid = threadIdx.x;
  if (blockIdx.x < 2048) {
    int wv = blockIdx.x * 4 + (tid >> 6);   // 8192 waves
    int lane = tid & 63;
    int jw = wv & 127;                      // j-word (32 j's)
    int it = wv >> 7;                       // i-tile of 64
    int i = it * 64 + lane;
    // lane reads its row's 32 adj ints (128 B contiguous); writes coalesced.
    const int4* p = reinterpret_cast<const int4*>(adj + (size_t)i * NODES + jw * 32);
    unsigned m = 0;
#pragma unroll
    for (int q = 0; q < 8; ++q) {
      int4 a = p[q];
      m |= (a.x != 0 ? 1u : 0u) << (q * 4);
      m |= (a.y != 0 ? 1u : 0u) << (q * 4 + 1);
      m |= (a.z != 0 ? 1u : 0u) << (q * 4 + 2);
      m |= (a.w != 0 ? 1u : 0u) << (q * 4 + 3);
    }
    bm[(size_t)jw * NODES + i] = m;
  } else {
    int idx = (blockIdx.x - 2048) * 256 + tid;  // float4 index
    const int NH4 = (NODES * KIN) / 4;          // 262144
    const int NW4 = (HFQ * KIN) / 4;            // 16384
    if (idx < NH4) {
      float4 v = reinterpret_cast<const float4*>(hin)[idx];
      ushort4 o = { f2bf(v.x), f2bf(v.y), f2bf(v.z), f2bf(v.w) };
      reinterpret_cast<ushort4*>(hB)[idx] = o;
    } else if (idx < NH4 + NW4) {
      int j = idx - NH4;
      float4 v = reinterpret_cast<const float4*>(Win)[j];
      ushort4 o = { f2bf(v.x), f2bf(v.y), f2bf(v.z), f2bf(v.w) };
      reinterpret_cast<ushort4*>(WB)[j] = o;
    }
  }
}

// ---- kernel 2: projection g = h @ W^T + b  (MFMA 16x16x32 bf16) ------------
// writes g32 [NODES][HFQ] fp32 and gT3: bf16 laid out in 16x16x32 A-fragment
// order for the attention kernel. Element (node j, col c):
//   jt=j>>5 (j-tile of 32), head=c>>6, ct=(c&63)>>4 (c-tile of 16),
//   lane = (j>>3 & 3)*16 + (c&15), r = j&7
//   short index = jt*8192 + head*2048 + ct*512 + lane*8 + r
__global__ __launch_bounds__(256) void proj_kernel(
    const unsigned short* __restrict__ hB, const unsigned short* __restrict__ WB,
    const float* __restrict__ bias,
    float* __restrict__ g32, unsigned short* __restrict__ gT3) {
  int wave = threadIdx.x >> 6, lane = threadIdx.x & 63;
  int tile = blockIdx.x * 4 + wave;       // 4096 tiles = 256 mtiles x 16 ntiles
  int mt = tile >> 4, nt = tile & 15;
  int m0 = mt * 16, n0 = nt * 16;
  int r = lane & 15, kg = lane >> 4;
  floatx4 acc = {0.f, 0.f, 0.f, 0.f};
  const short8* Ap = reinterpret_cast<const short8*>(hB + (m0 + r) * KIN + kg * 8);
  const short8* Bp = reinterpret_cast<const short8*>(WB + (n0 + r) * KIN + kg * 8);
#pragma unroll
  for (int kb = 0; kb < 8; ++kb) {
    short8 a = Ap[kb * 4];   // advance 32 shorts per K-step
    short8 b = Bp[kb * 4];
    acc = __builtin_amdgcn_mfma_f32_16x16x32_bf16(a, b, acc, 0, 0, 0);
  }
  int col = n0 + r;
  float bv = bias[col];
  int head = col >> 6, ct = (col & 63) >> 4, c15 = col & 15;
#pragma unroll
  for (int q = 0; q < 4; ++q) {
    int row = m0 + kg * 4 + q;            // C/D layout: row=(lane>>4)*4+reg, col=lane&15
    float v = acc[q] + bv;
    g32[row * HFQ + col] = v;
    int si = (row >> 5) * 8192 + head * 2048 + ct * 512 +
             (((row >> 3) & 3) * 16 + c15) * 8 + (row & 7);
    gT3[si] = f2bf(v);
  }
}

// ---- kernel 3: src/dst per (node, head) -> factorized exp terms ------------
// srcP[n][h] = (exp(s), exp(0.2s), exp(-s), 0), s incl. bias
// eP[h][n]   = (bf16(exp(0.2d)) << 16) | bf16(exp(d))   -- 64 KB, L1-resident
__global__ __launch_bounds__(256) void srcdst_kernel(
    const float* __restrict__ g32, const float* __restrict__ attn_w,
    const float* __restrict__ attn_b,
    float4* __restrict__ srcP, unsigned* __restrict__ eP) {
  int wave = threadIdx.x >> 6, lane = threadIdx.x & 63;
  int n = blockIdx.x * 4 + wave;
  float aws = attn_w[lane], awd = attn_w[64 + lane];
  float ab = attn_b[0];
#pragma unroll
  for (int hh = 0; hh < NHEAD; ++hh) {
    float v = g32[n * HFQ + hh * NF + lane];
    float s = v * aws, d = v * awd;
#pragma unroll
    for (int m = 32; m >= 1; m >>= 1) {
      s += __shfl_xor(s, m, 64);
      d += __shfl_xor(d, m, 64);
    }
    if (lane == 0) {
      s += ab;
      float4 sp;
      sp.x = exp2f(s * L2E);
      sp.y = exp2f(0.2f * s * L2E);
      sp.z = exp2f(-s * L2E);
      sp.w = 0.f;
      srcP[n * NHEAD + hh] = sp;
      float e1 = exp2f(d * L2E), e2 = exp2f(0.2f * d * L2E);
      eP[hh * NODES + n] = ((unsigned)f2bf(e2) << 16) | (unsigned)f2bf(e1);
    }
  }
}

// ---- kernel 4: fused attention, 16x16x32 MFMA, 8 waves/SIMD ----------------
// grid (NP, 256): blockIdx.x = j-partition (linear%8 -> one partition per XCD),
// blockIdx.y = i-tile of 16 rows. block 256 = 4 waves (1 head each).
// D[c][i] = sum_j g[c,j]*w[j,i]: A = g (gT3, contiguous 1KB/wave-load),
// B = w in-register. B layout: lane&15 = i, k = 8*(lane>>4)+r = j.
// 2048 blocks -> 8 blocks/CU -> 8 waves/SIMD (VGPR capped via launch_bounds).
__global__ __launch_bounds__(256, 8) void attn_kernel(
    const unsigned* __restrict__ bm, const unsigned short* __restrict__ gT3,
    const float4* __restrict__ srcP, const unsigned* __restrict__ eP,
    float* __restrict__ pnum, float* __restrict__ pden, int JP) {
  int tid = threadIdx.x;
  int hh = tid >> 6, lane = tid & 63;
  int il = lane & 15, kg = lane >> 4;
  int part = blockIdx.x, itile = blockIdx.y;
  int jstart = part * JP;
  int i = itile * 16 + il;                // attention row this lane owns

  float4 sp = srcP[i * NHEAD + hh];
  float es1 = sp.x, es2 = sp.y, thr = sp.z;

  floatx4 acc0 = {0.f, 0.f, 0.f, 0.f};
  floatx4 acc1 = acc0, acc2 = acc0, acc3 = acc0, accd = acc0;

  short8 ones;
#pragma unroll
  for (int r = 0; r < 8; ++r) ones[r] = (short)0x3F80;  // bf16 1.0

  const unsigned* epb = eP + hh * NODES;
  const unsigned short* Ab = gT3 + hh * 2048;

  int nsteps = JP / 32;
  for (int stp = 0; stp < nsteps; ++stp) {
    int j0 = jstart + stp * 32;
    int jt = j0 >> 5;
    unsigned mwd = bm[(size_t)jt * NODES + i];              // coalesced dword
    unsigned mb = (mwd >> (kg * 8)) & 0xFFu;
    const unsigned* ep = epb + j0 + kg * 8;
    uint4 ea = *reinterpret_cast<const uint4*>(ep);         // broadcast in group
    uint4 eb = *reinterpret_cast<const uint4*>(ep + 4);
    unsigned ev[8] = {ea.x, ea.y, ea.z, ea.w, eb.x, eb.y, eb.z, eb.w};
    short8 bfr;
#pragma unroll
    for (int r = 0; r < 8; ++r) {
      float e1f = __builtin_bit_cast(float, ev[r] << 16);
      float e2f = __builtin_bit_cast(float, ev[r] & 0xFFFF0000u);
      bool sel = e1f >= thr;
      float w = (sel ? es1 : es2) * (sel ? e1f : e2f);
      w = (mb & (1u << r)) ? w : 0.f;
      bfr[r] = (short)f2bf(w);
    }
    const unsigned short* At = Ab + (size_t)jt * 8192;
    const short8 a0 = *reinterpret_cast<const short8*>(At + 0 * 512 + lane * 8);
    const short8 a1 = *reinterpret_cast<const short8*>(At + 1 * 512 + lane * 8);
    const short8 a2 = *reinterpret_cast<const short8*>(At + 2 * 512 + lane * 8);
    const short8 a3 = *reinterpret_cast<const short8*>(At + 3 * 512 + lane * 8);
    acc0 = __builtin_amdgcn_mfma_f32_16x16x32_bf16(a0, bfr, acc0, 0, 0, 0);
    acc1 = __builtin_amdgcn_mfma_f32_16x16x32_bf16(a1, bfr, acc1, 0, 0, 0);
    acc2 = __builtin_amdgcn_mfma_f32_16x16x32_bf16(a2, bfr, acc2, 0, 0, 0);
    acc3 = __builtin_amdgcn_mfma_f32_16x16x32_bf16(a3, bfr, acc3, 0, 0, 0);
    accd = __builtin_amdgcn_mfma_f32_16x16x32_bf16(ones, bfr, accd, 0, 0, 0);
  }

  // denominator: all c-rows of accd identical; col = il
  if (kg == 0)
    pden[(size_t)part * (NODES * NHEAD) + i * NHEAD + hh] = accd[0];

  // numerator: C/D layout col=lane&15 (=i), row c_in_tile = kg*4 + q
  float* pbase = pnum + (size_t)part * (NODES * HFQ) + (size_t)i * HFQ + hh * NF;
#pragma unroll
  for (int q = 0; q < 4; ++q) {
    int c = kg * 4 + q;
    pbase[c] = acc0[q];
    pbase[16 + c] = acc1[q];
    pbase[32 + c] = acc2[q];
    pbase[48 + c] = acc3[q];
  }
}

// ---- kernel 5: combine partials, normalize, mean over heads ----------------
__global__ __launch_bounds__(256) void combine_kernel(
    const float* __restrict__ pnum, const float* __restrict__ pden,
    float* __restrict__ out, int NP) {
  int idx = blockIdx.x * 256 + threadIdx.x;
  int i = idx >> 6, f = idx & 63;
  float o = 0.f;
#pragma unroll
  for (int hh = 0; hh < NHEAD; ++hh) {
    float num = 0.f, den = 0.f;
    for (int p = 0; p < NP; ++p) {
      num += pnum[p * (NODES * HFQ) + i * HFQ + hh * NF + f];
      den += pden[p * (NODES * NHEAD) + i * NHEAD + hh];
    }
    o += num / den;
  }
  out[idx] = 0.25f * o;
}

extern "C" void kernel_launch(void* const* d_in, const int* in_sizes, int n_in,
                              void* d_out, int out_size, void* d_ws, size_t ws_size,
                              hipStream_t stream) {
  const float* hin = (const float*)d_in[0];
  const int* adj   = (const int*)d_in[1];
  const float* W   = (const float*)d_in[2];
  const float* b   = (const float*)d_in[3];
  const float* aw  = (const float*)d_in[4];
  const float* ab  = (const float*)d_in[5];
  float* out = (float*)d_out;
  char* ws = (char*)d_ws;

  unsigned short* hB  = (unsigned short*)(ws + 0x000000);  // 2 MB
  unsigned short* WB  = (unsigned short*)(ws + 0x200000);  // 128 KB
  float* g32          = (float*)(ws + 0x400000);           // 4 MB
  unsigned short* gT3 = (unsigned short*)(ws + 0x800000);  // 2 MB (frag-ordered)
  float4* srcP        = (float4*)(ws + 0xA00000);          // 256 KB
  unsigned* eP        = (unsigned*)(ws + 0xA40000);        // 64 KB
  unsigned* bm        = (unsigned*)(ws + 0xA60000);        // 2 MB bitmask
  float* pden         = (float*)(ws + 0xC60000);           // up to 512 KB
  float* pnum         = (float*)(ws + 0xD00000);           // NP * 4 MB
  const size_t base = 0xD00000;

  int NP = 2;
  if (ws_size >= base + 8ull * NODES * HFQ * 4) NP = 8;
  else if (ws_size >= base + 4ull * NODES * HFQ * 4) NP = 4;
  int JP = NODES / NP;

  pack_prep_kernel<<<2048 + 1088, 256, 0, stream>>>(adj, bm, hin, W, hB, WB);
  proj_kernel<<<1024, 256, 0, stream>>>(hB, WB, b, g32, gT3);
  srcdst_kernel<<<1024, 256, 0, stream>>>(g32, aw, ab, srcP, eP);
  attn_kernel<<<dim3(NP, 256), 256, 0, stream>>>(bm, gT3, srcP, eP, pnum, pden, JP);
  combine_kernel<<<1024, 256, 0, stream>>>(pnum, pden, out, NP);
}

// Round 7
// 71.200 us; speedup vs baseline: 1.5155x; 1.1367x over previous
//
#include <hip/hip_runtime.h>
#include <stdint.h>

// GAT layer: N=4096 nodes, IN=256, H=4 heads, F=64 out/head.
constexpr int NODES = 4096;
constexpr int KIN   = 256;
constexpr int NHEAD = 4;
constexpr int NF    = 64;
constexpr int HFQ   = 256;   // NHEAD*NF
#define L2E 1.44269504088896340736f

typedef __attribute__((ext_vector_type(8))) short short8;
typedef __attribute__((ext_vector_type(4))) float floatx4;

static __device__ __forceinline__ unsigned short f2bf(float f) {
  return __builtin_bit_cast(unsigned short, (__bf16)f);
}

// ---- kernel 1: adjacency -> transposed bitmask  +  fp32->bf16 prep ---------
// bm[jw][i] bit b = (adj[i][jw*32+b] != 0).  bm is 2 MB -> L2-resident.
// Blocks < 2048: pack. Blocks >= 2048: bf16 conversion of h and W.
__global__ __launch_bounds__(256) void pack_prep_kernel(
    const int* __restrict__ adj, unsigned* __restrict__ bm,
    const float* __restrict__ hin, const float* __restrict__ Win,
    unsigned short* __restrict__ hB, unsigned short* __restrict__ WB) {
  int tid = threadIdx.x;
  if (blockIdx.x < 2048) {
    int wv = blockIdx.x * 4 + (tid >> 6);   // 8192 waves
    int lane = tid & 63;
    int jw = wv & 127;                      // j-word (32 j's)
    int it = wv >> 7;                       // i-tile of 64
    int i = it * 64 + lane;
    const int4* p = reinterpret_cast<const int4*>(adj + (size_t)i * NODES + jw * 32);
    unsigned m = 0;
#pragma unroll
    for (int q = 0; q < 8; ++q) {
      int4 a = p[q];
      m |= (a.x != 0 ? 1u : 0u) << (q * 4);
      m |= (a.y != 0 ? 1u : 0u) << (q * 4 + 1);
      m |= (a.z != 0 ? 1u : 0u) << (q * 4 + 2);
      m |= (a.w != 0 ? 1u : 0u) << (q * 4 + 3);
    }
    bm[(size_t)jw * NODES + i] = m;
  } else {
    int idx = (blockIdx.x - 2048) * 256 + tid;  // float4 index
    const int NH4 = (NODES * KIN) / 4;          // 262144
    const int NW4 = (HFQ * KIN) / 4;            // 16384
    if (idx < NH4) {
      float4 v = reinterpret_cast<const float4*>(hin)[idx];
      ushort4 o = { f2bf(v.x), f2bf(v.y), f2bf(v.z), f2bf(v.w) };
      reinterpret_cast<ushort4*>(hB)[idx] = o;
    } else if (idx < NH4 + NW4) {
      int j = idx - NH4;
      float4 v = reinterpret_cast<const float4*>(Win)[j];
      ushort4 o = { f2bf(v.x), f2bf(v.y), f2bf(v.z), f2bf(v.w) };
      reinterpret_cast<ushort4*>(WB)[j] = o;
    }
  }
}

// ---- kernel 2: fused projection + src/dst factor tables --------------------
// grid 256 blocks x 4 waves; block = 16 rows x all 256 cols, wave = one head.
// Writes gT3 (16x16x32 A-fragment order), srcP[n][h]=(exp(s),exp(0.2s)),
// eP[h][n] = (bf16(exp(0.2d))<<16) | bf16(exp(d)).  No fp32 g buffer.
__global__ __launch_bounds__(256) void proj_kernel(
    const unsigned short* __restrict__ hB, const unsigned short* __restrict__ WB,
    const float* __restrict__ bias, const float* __restrict__ attn_w,
    const float* __restrict__ attn_b,
    unsigned short* __restrict__ gT3, float2* __restrict__ srcP,
    unsigned* __restrict__ eP) {
  int h = threadIdx.x >> 6, lane = threadIdx.x & 63;
  int m0 = blockIdx.x * 16;
  int r = lane & 15, kg = lane >> 4;
  floatx4 acc[4] = {{0.f,0.f,0.f,0.f},{0.f,0.f,0.f,0.f},{0.f,0.f,0.f,0.f},{0.f,0.f,0.f,0.f}};
  const short8* Ap = reinterpret_cast<const short8*>(hB + (m0 + r) * KIN + kg * 8);
#pragma unroll
  for (int kb = 0; kb < 8; ++kb) {
    short8 a = Ap[kb * 4];
#pragma unroll
    for (int nt = 0; nt < 4; ++nt) {
      const short8 b = *reinterpret_cast<const short8*>(
          WB + (h * NF + nt * 16 + r) * KIN + kg * 8 + kb * 32);
      acc[nt] = __builtin_amdgcn_mfma_f32_16x16x32_bf16(a, b, acc[nt], 0, 0, 0);
    }
  }
  // bias + gT3 write + per-lane src/dst partials over this lane's 4 cols
  float ps[4] = {0.f,0.f,0.f,0.f}, pd[4] = {0.f,0.f,0.f,0.f};
#pragma unroll
  for (int nt = 0; nt < 4; ++nt) {
    int f = nt * 16 + r;
    float bv = bias[h * NF + f];
    float was = attn_w[f], wad = attn_w[64 + f];
#pragma unroll
    for (int q = 0; q < 4; ++q) {
      int row = m0 + kg * 4 + q;          // C/D: row=(lane>>4)*4+q, col=lane&15
      float v = acc[nt][q] + bv;
      int si = (row >> 5) * 8192 + h * 2048 + nt * 512 +
               (((row >> 3) & 3) * 16 + r) * 8 + (row & 7);
      gT3[si] = f2bf(v);
      ps[q] += v * was;
      pd[q] += v * wad;
    }
  }
  // butterfly over the 16 lanes of each kg group (lane bits 0..3)
#pragma unroll
  for (int m = 8; m >= 1; m >>= 1) {
#pragma unroll
    for (int q = 0; q < 4; ++q) {
      ps[q] += __shfl_xor(ps[q], m, 64);
      pd[q] += __shfl_xor(pd[q], m, 64);
    }
  }
  float ab = attn_b[0];
  if ((lane & 15) == 0) {                 // one lane per kg writes 4 rows
#pragma unroll
    for (int q = 0; q < 4; ++q) {
      int row = m0 + kg * 4 + q;
      float s = ps[q] + ab, d = pd[q];
      float2 sp;
      sp.x = exp2f(s * L2E);
      sp.y = exp2f(0.2f * s * L2E);
      srcP[row * NHEAD + h] = sp;
      float e1 = exp2f(d * L2E), e2 = exp2f(0.2f * d * L2E);
      eP[h * NODES + row] = ((unsigned)f2bf(e2) << 16) | (unsigned)f2bf(e1);
    }
  }
}

// ---- kernel 3: fused attention, 16x16x32 MFMA, 8 waves/SIMD ----------------
// grid (NP, 256): blockIdx.x = j-partition (linear%8 -> one per XCD),
// blockIdx.y = i-tile of 16 rows. block 256 = 4 waves (1 head each).
// w = max(es1*e1, es2*e2)  (== exp(lrelu(s+d)), exact identity), masked by bm.
// bm/ep are software-pipelined one step ahead (named regs, static indexing).
__global__ __launch_bounds__(256, 8) void attn_kernel(
    const unsigned* __restrict__ bm, const unsigned short* __restrict__ gT3,
    const float2* __restrict__ srcP, const unsigned* __restrict__ eP,
    float* __restrict__ pnum, float* __restrict__ pden, int JP) {
  int tid = threadIdx.x;
  int hh = tid >> 6, lane = tid & 63;
  int il = lane & 15, kg = lane >> 4;
  int part = blockIdx.x, itile = blockIdx.y;
  int jstart = part * JP;
  int i = itile * 16 + il;                // attention row this lane owns

  float2 sp = srcP[i * NHEAD + hh];
  float es1 = sp.x, es2 = sp.y;

  floatx4 acc0 = {0.f, 0.f, 0.f, 0.f};
  floatx4 acc1 = acc0, acc2 = acc0, acc3 = acc0, accd = acc0;

  short8 ones;
#pragma unroll
  for (int r = 0; r < 8; ++r) ones[r] = (short)0x3F80;  // bf16 1.0

  int jt0 = jstart >> 5;
  const unsigned* bmp = bm + (size_t)jt0 * NODES + i;
  const unsigned* epp = eP + hh * NODES + jstart + kg * 8;
  const unsigned short* Atp = gT3 + (size_t)jt0 * 8192 + hh * 2048 + lane * 8;

  unsigned mwd = *bmp;
  uint4 ea = *reinterpret_cast<const uint4*>(epp);
  uint4 eb = *reinterpret_cast<const uint4*>(epp + 4);

  int nsteps = JP / 32;

#define STEP_BODY {                                                         \
    unsigned mb = (mwd >> (kg * 8)) & 0xFFu;                                \
    unsigned ev[8] = {ea.x, ea.y, ea.z, ea.w, eb.x, eb.y, eb.z, eb.w};      \
    short8 bfr;                                                             \
    _Pragma("unroll")                                                       \
    for (int r = 0; r < 8; ++r) {                                           \
      float e1f = __builtin_bit_cast(float, ev[r] << 16);                   \
      float e2f = __builtin_bit_cast(float, ev[r] & 0xFFFF0000u);           \
      float w = fmaxf(es1 * e1f, es2 * e2f);                                \
      w = (mb & (1u << r)) ? w : 0.f;                                       \
      bfr[r] = (short)f2bf(w);                                              \
    }                                                                       \
    const short8 a0 = *reinterpret_cast<const short8*>(Atp);                \
    const short8 a1 = *reinterpret_cast<const short8*>(Atp + 512);          \
    const short8 a2 = *reinterpret_cast<const short8*>(Atp + 1024);         \
    const short8 a3 = *reinterpret_cast<const short8*>(Atp + 1536);         \
    acc0 = __builtin_amdgcn_mfma_f32_16x16x32_bf16(a0, bfr, acc0, 0, 0, 0); \
    acc1 = __builtin_amdgcn_mfma_f32_16x16x32_bf16(a1, bfr, acc1, 0, 0, 0); \
    acc2 = __builtin_amdgcn_mfma_f32_16x16x32_bf16(a2, bfr, acc2, 0, 0, 0); \
    acc3 = __builtin_amdgcn_mfma_f32_16x16x32_bf16(a3, bfr, acc3, 0, 0, 0); \
    accd = __builtin_amdgcn_mfma_f32_16x16x32_bf16(ones, bfr, accd, 0, 0, 0);\
  }

  for (int stp = 0; stp < nsteps - 1; ++stp) {
    unsigned mwd_n = bmp[NODES];                                  // prefetch
    uint4 ea_n = *reinterpret_cast<const uint4*>(epp + 32);
    uint4 eb_n = *reinterpret_cast<const uint4*>(epp + 36);
    STEP_BODY;
    mwd = mwd_n; ea = ea_n; eb = eb_n;
    bmp += NODES; epp += 32; Atp += 8192;
  }
  STEP_BODY;                                                      // last step
#undef STEP_BODY

  // denominator: all c-rows of accd identical; col = il
  if (kg == 0)
    pden[(size_t)part * (NODES * NHEAD) + i * NHEAD + hh] = accd[0];

  // numerator: C/D layout col=lane&15 (=i), row c_in_tile = kg*4 + q
  float* pbase = pnum + (size_t)part * (NODES * HFQ) + (size_t)i * HFQ + hh * NF;
#pragma unroll
  for (int q = 0; q < 4; ++q) {
    int c = kg * 4 + q;
    pbase[c] = acc0[q];
    pbase[16 + c] = acc1[q];
    pbase[32 + c] = acc2[q];
    pbase[48 + c] = acc3[q];
  }
}

// ---- kernel 4: combine partials, normalize, mean over heads ----------------
__global__ __launch_bounds__(256) void combine_kernel(
    const float* __restrict__ pnum, const float* __restrict__ pden,
    float* __restrict__ out, int NP) {
  int idx = blockIdx.x * 256 + threadIdx.x;
  int i = idx >> 6, f = idx & 63;
  float o = 0.f;
#pragma unroll
  for (int hh = 0; hh < NHEAD; ++hh) {
    float num = 0.f, den = 0.f;
    for (int p = 0; p < NP; ++p) {
      num += pnum[p * (NODES * HFQ) + i * HFQ + hh * NF + f];
      den += pden[p * (NODES * NHEAD) + i * NHEAD + hh];
    }
    o += num / den;
  }
  out[idx] = 0.25f * o;
}

extern "C" void kernel_launch(void* const* d_in, const int* in_sizes, int n_in,
                              void* d_out, int out_size, void* d_ws, size_t ws_size,
                              hipStream_t stream) {
  const float* hin = (const float*)d_in[0];
  const int* adj   = (const int*)d_in[1];
  const float* W   = (const float*)d_in[2];
  const float* b   = (const float*)d_in[3];
  const float* aw  = (const float*)d_in[4];
  const float* ab  = (const float*)d_in[5];
  float* out = (float*)d_out;
  char* ws = (char*)d_ws;

  unsigned short* hB  = (unsigned short*)(ws + 0x000000);  // 2 MB
  unsigned short* WB  = (unsigned short*)(ws + 0x200000);  // 128 KB
  unsigned short* gT3 = (unsigned short*)(ws + 0x400000);  // 2 MB (frag-ordered)
  float2* srcP        = (float2*)(ws + 0x600000);          // 128 KB
  unsigned* eP        = (unsigned*)(ws + 0x620000);        // 64 KB
  unsigned* bm        = (unsigned*)(ws + 0x640000);        // 2 MB bitmask
  float* pden         = (float*)(ws + 0x840000);           // up to 512 KB
  float* pnum         = (float*)(ws + 0x900000);           // NP * 4 MB
  const size_t base = 0x900000;

  int NP = 2;
  if (ws_size >= base + 8ull * NODES * HFQ * 4) NP = 8;
  else if (ws_size >= base + 4ull * NODES * HFQ * 4) NP = 4;
  int JP = NODES / NP;

  pack_prep_kernel<<<2048 + 1088, 256, 0, stream>>>(adj, bm, hin, W, hB, WB);
  proj_kernel<<<256, 256, 0, stream>>>(hB, WB, b, aw, ab, gT3, srcP, eP);
  attn_kernel<<<dim3(NP, 256), 256, 0, stream>>>(bm, gT3, srcP, eP, pnum, pden, JP);
  combine_kernel<<<1024, 256, 0, stream>>>(pnum, pden, out, NP);
}